// Round 17
// baseline (172.741 us; speedup 1.0000x reference)
//
#include <hip/hip_runtime.h>

#define EPS_LN 1e-5f

constexpr int Dm   = 768;
constexpr int Bb   = 4;
constexpr int Ls   = 1024;
constexpr int Hh   = 12;
constexpr int HD   = 64;
constexpr int ROWS = Bb * Ls;            // 4096
constexpr size_t S = (size_t)ROWS * Dm;  // 3,145,728
constexpr size_t WSZ = (size_t)Dm * Dm;  // 589,824

typedef __attribute__((ext_vector_type(8))) short bf16x8;
typedef __attribute__((ext_vector_type(4))) float f32x4;
typedef const __attribute__((address_space(1))) unsigned int* gas_p;
typedef __attribute__((address_space(3))) unsigned int* las_p;

__device__ __forceinline__ unsigned short f2bf(float f) {
  unsigned int u = __float_as_uint(f);
  u += 0x7fffu + ((u >> 16) & 1u);   // RNE
  return (unsigned short)(u >> 16);
}
__device__ __forceinline__ void gl_lds16(const unsigned short* g, unsigned short* l) {
  __builtin_amdgcn_global_load_lds((gas_p)g, (las_p)l, 16, 0, 0);
}

// =============== fused prep: 5 weight transposes + centers(wave-per-row) + LN1(wave-per-row) ===============
// R17: launched TWICE as a timing probe (pure function of harness inputs -> idempotent;
// stream-ordered -> no race; dur_us delta vs R16 == prep's cost, invisible in top-5
// because the 43us workspace fills mask everything shorter).
__global__ void __launch_bounds__(256) prep_kernel(
    const float* __restrict__ W0, const float* __restrict__ W1,
    const float* __restrict__ W2, const float* __restrict__ W3,
    const float* __restrict__ W4, unsigned short* __restrict__ wtBase,
    const float* __restrict__ centers, const float* __restrict__ ls,
    unsigned short* __restrict__ cb, float* __restrict__ cn,
    const float* __restrict__ x, const float* __restrict__ scale,
    const float* __restrict__ shift, unsigned short* __restrict__ hb)
{
  __shared__ float smem[64 * 65];
  int bx = blockIdx.x, t = threadIdx.x;
  if (bx < 720) {
    int w = bx / 144, rem = bx - w * 144;
    int ky = rem / 12, nx = rem - ky * 12;
    const float* W = w == 0 ? W0 : w == 1 ? W1 : w == 2 ? W2 : w == 3 ? W3 : W4;
    unsigned short* WT = wtBase + (size_t)w * WSZ;
    int k0 = ky * 64, n0 = nx * 64;
    int c = t & 63, r4 = t >> 6;
    #pragma unroll
    for (int p = 0; p < 16; p++) {
      int r = p * 4 + r4;
      smem[r * 65 + c] = W[(size_t)(k0 + r) * Dm + n0 + c];
    }
    __syncthreads();
    #pragma unroll
    for (int p = 0; p < 16; p++) {
      int r = p * 4 + r4;
      WT[(size_t)(n0 + r) * Dm + k0 + c] = f2bf(smem[c * 65 + r]);
    }
  } else if (bx < 912) {
    // centers: wave-per-row, zero barriers
    int lane = t & 63;
    int j = (bx - 720) * 4 + (t >> 6);
    size_t base = (size_t)j * Dm;
    float s = 0.f;
    #pragma unroll
    for (int jj = 0; jj < 3; jj++) {
      int k4 = 4 * (lane + 64 * jj);
      float4 cv = *(const float4*)&centers[base + k4];
      float4 lv = *(const float4*)&ls[k4];
      float4 c;
      c.x = cv.x / lv.x; c.y = cv.y / lv.y; c.z = cv.z / lv.z; c.w = cv.w / lv.w;
      ushort4 o4;
      o4.x = f2bf(c.x); o4.y = f2bf(c.y); o4.z = f2bf(c.z); o4.w = f2bf(c.w);
      *(ushort4*)&cb[base + k4] = o4;
      s += c.x*c.x + c.y*c.y + c.z*c.z + c.w*c.w;
    }
    #pragma unroll
    for (int m = 1; m < 64; m <<= 1) s += __shfl_xor(s, m);
    if (lane == 0) cn[j] = s;
  } else {
    // LN1: wave-per-row, zero barriers
    int lane = t & 63;
    int row = (bx - 912) * 4 + (t >> 6);
    size_t base = (size_t)row * Dm;
    float4 v[3];
    #pragma unroll
    for (int j = 0; j < 3; j++)
      v[j] = *(const float4*)&x[base + 4 * (lane + 64 * j)];
    float sum = 0.f;
    #pragma unroll
    for (int j = 0; j < 3; j++) sum += v[j].x + v[j].y + v[j].z + v[j].w;
    #pragma unroll
    for (int m = 1; m < 64; m <<= 1) sum += __shfl_xor(sum, m);
    float mean = sum * (1.0f / Dm);
    float4 d[3];
    float vs = 0.f;
    #pragma unroll
    for (int j = 0; j < 3; j++) {
      d[j].x = v[j].x - mean; d[j].y = v[j].y - mean;
      d[j].z = v[j].z - mean; d[j].w = v[j].w - mean;
      vs += d[j].x*d[j].x + d[j].y*d[j].y + d[j].z*d[j].z + d[j].w*d[j].w;
    }
    #pragma unroll
    for (int m = 1; m < 64; m <<= 1) vs += __shfl_xor(vs, m);
    float rstd = rsqrtf(vs * (1.0f / Dm) + EPS_LN);
    #pragma unroll
    for (int j = 0; j < 3; j++) {
      int c4 = 4 * (lane + 64 * j);
      float4 sc = *(const float4*)&scale[c4];
      float4 sh = *(const float4*)&shift[c4];
      ushort4 o4;
      o4.x = f2bf(sc.x * d[j].x * rstd + sh.x);
      o4.y = f2bf(sc.y * d[j].y * rstd + sh.y);
      o4.z = f2bf(sc.z * d[j].z * rstd + sh.z);
      o4.w = f2bf(sc.w * d[j].w * rstd + sh.w);
      *(ushort4*)&hb[base + c4] = o4;
    }
  }
}

// ---- LN2 + /ls (wave-per-row) + fused degenerate-RBF output (R12-proven) ----
__global__ void __launch_bounds__(256) ln2_kernel(
    const float* __restrict__ xin, const float* __restrict__ scale,
    const float* __restrict__ shift, const float* __restrict__ ls,
    const float* __restrict__ cn, const float* __restrict__ bias,
    unsigned short* __restrict__ o, float* __restrict__ hn,
    float* __restrict__ outF)
{
  int lane = threadIdx.x & 63;
  int row = blockIdx.x * 4 + (threadIdx.x >> 6);
  size_t base = (size_t)row * Dm;
  float4 v[3];
  #pragma unroll
  for (int j = 0; j < 3; j++)
    v[j] = *(const float4*)&xin[base + 4 * (lane + 64 * j)];
  float sum = 0.f;
  #pragma unroll
  for (int j = 0; j < 3; j++) sum += v[j].x + v[j].y + v[j].z + v[j].w;
  #pragma unroll
  for (int m = 1; m < 64; m <<= 1) sum += __shfl_xor(sum, m);
  float mean = sum * (1.0f / Dm);
  float4 d[3];
  float vs = 0.f;
  #pragma unroll
  for (int j = 0; j < 3; j++) {
    d[j].x = v[j].x - mean; d[j].y = v[j].y - mean;
    d[j].z = v[j].z - mean; d[j].w = v[j].w - mean;
    vs += d[j].x*d[j].x + d[j].y*d[j].y + d[j].z*d[j].z + d[j].w*d[j].w;
  }
  #pragma unroll
  for (int m = 1; m < 64; m <<= 1) vs += __shfl_xor(vs, m);
  float rstd = rsqrtf(vs * (1.0f / Dm) + EPS_LN);
  float hsum = 0.f;
  #pragma unroll
  for (int j = 0; j < 3; j++) {
    int c4 = 4 * (lane + 64 * j);
    float4 sc = *(const float4*)&scale[c4];
    float4 sh = *(const float4*)&shift[c4];
    float4 lv = *(const float4*)&ls[c4];
    float4 hv;
    hv.x = (sc.x * d[j].x * rstd + sh.x) / lv.x;
    hv.y = (sc.y * d[j].y * rstd + sh.y) / lv.y;
    hv.z = (sc.z * d[j].z * rstd + sh.z) / lv.z;
    hv.w = (sc.w * d[j].w * rstd + sh.w) / lv.w;
    ushort4 o4;
    o4.x = f2bf(hv.x); o4.y = f2bf(hv.y); o4.z = f2bf(hv.z); o4.w = f2bf(hv.w);
    *(ushort4*)&o[base + c4] = o4;
    hsum += hv.x*hv.x + hv.y*hv.y + hv.z*hv.z + hv.w*hv.w;
  }
  #pragma unroll
  for (int m = 1; m < 64; m <<= 1) hsum += __shfl_xor(hsum, m);
  if (lane == 0) hn[row] = hsum;

  float cm = 0.f;
  #pragma unroll
  for (int j = 0; j < 12; j++) cm = fmaxf(cm, cn[lane + 64 * j]);
  #pragma unroll
  for (int m = 1; m < 64; m <<= 1) cm = fmaxf(cm, __shfl_xor(cm, m));
  float a = sqrtf(hsum), bq = sqrtf(cm);
  if ((a > bq) && ((a - bq) * (a - bq) > 300.0f)) {
    #pragma unroll
    for (int j = 0; j < 3; j++) {
      int c4 = 4 * (lane + 64 * j);
      float4 xv = v[j];
      float4 bv = *(const float4*)&bias[c4];
      float4 ov;
      ov.x = xv.x + bv.x; ov.y = xv.y + bv.y; ov.z = xv.z + bv.z; ov.w = xv.w + bv.w;
      *(float4*)&outF[base + c4] = ov;
    }
  }
}

// =============== QKV 3-in-1 GEMM (R0-proven) + Q pre-scaled by 0.125 (exact) ===============
__global__ void __launch_bounds__(256) gemm_qkv(
    const unsigned short* __restrict__ Abf,
    const unsigned short* __restrict__ wqT,
    const unsigned short* __restrict__ wkT,
    const unsigned short* __restrict__ wvT,
    unsigned short* __restrict__ qb,
    unsigned short* __restrict__ kb,
    unsigned short* __restrict__ vbt)
{
  int m0 = blockIdx.y * 64, n0 = blockIdx.x * 64;
  __shared__ unsigned short sm[4096 + 3 * 4096];
  int tid = threadIdx.x;
  int lane = tid & 63, wave = tid >> 6;
  int quad = lane >> 4, l15 = lane & 15;
  int wr = (wave >> 1) << 5, wc = (wave & 1) << 5;

  f32x4 acc[3][2][2];
  #pragma unroll
  for (int w = 0; w < 3; w++)
    #pragma unroll
    for (int i = 0; i < 2; i++)
      #pragma unroll
      for (int j = 0; j < 2; j++) acc[w][i][j] = (f32x4){0.f, 0.f, 0.f, 0.f};

  const unsigned short* gA = Abf + (size_t)(m0 + (tid >> 2)) * Dm + ((tid & 3) << 3);
  size_t bOff = (size_t)(n0 + (tid >> 2)) * Dm + ((tid & 3) << 3);
  const unsigned short* gB[3] = { wqT + bOff, wkT + bOff, wvT + bOff };

  union Frag { bf16x8 v; ushort4 h[2]; };

  for (int k0 = 0; k0 < Dm; k0 += 64) {
    gl_lds16(gA + k0,      &sm[tid * 8]);
    gl_lds16(gA + k0 + 32, &sm[2048 + tid * 8]);
    #pragma unroll
    for (int w = 0; w < 3; w++) {
      gl_lds16(gB[w] + k0,      &sm[4096 + w * 4096 + tid * 8]);
      gl_lds16(gB[w] + k0 + 32, &sm[4096 + w * 4096 + 2048 + tid * 8]);
    }
    __syncthreads();
    Frag af[2][2];
    #pragma unroll
    for (int kc = 0; kc < 2; kc++)
      #pragma unroll
      for (int mi = 0; mi < 2; mi++)
        af[kc][mi].v = *(const bf16x8*)&sm[kc * 2048 + (wr + mi * 16 + l15) * 32 + quad * 8];
    #pragma unroll
    for (int w = 0; w < 3; w++)
      #pragma unroll
      for (int kc = 0; kc < 2; kc++)
        #pragma unroll
        for (int ni = 0; ni < 2; ni++) {
          Frag bf;
          bf.v = *(const bf16x8*)&sm[4096 + w * 4096 + kc * 2048 + (wc + ni * 16 + l15) * 32 + quad * 8];
          #pragma unroll
          for (int mi = 0; mi < 2; mi++)
            acc[w][mi][ni] = __builtin_amdgcn_mfma_f32_16x16x32_bf16(
                af[kc][mi].v, bf.v, acc[w][mi][ni], 0, 0, 0);
        }
    __syncthreads();
  }

  #pragma unroll
  for (int w = 0; w < 2; w++) {
    unsigned short* ob = w ? kb : qb;
    float scl = w ? 1.0f : 0.125f;     // Q pre-scale (exact)
    #pragma unroll
    for (int mi = 0; mi < 2; mi++)
      #pragma unroll
      for (int ni = 0; ni < 2; ni++)
        #pragma unroll
        for (int rg = 0; rg < 4; rg++) {
          int gr = m0 + wr + mi * 16 + quad * 4 + rg;
          int gc = n0 + wc + ni * 16 + l15;
          ob[(size_t)gr * Dm + gc] = f2bf(acc[w][mi][ni][rg] * scl);
        }
  }
  #pragma unroll
  for (int mi = 0; mi < 2; mi++)
    #pragma unroll
    for (int ni = 0; ni < 2; ni++)
      #pragma unroll
      for (int rg = 0; rg < 4; rg++) {
        int rl = wr + mi * 16 + quad * 4 + rg;
        int cl = wc + ni * 16 + l15;
        sm[cl * 72 + rl] = f2bf(acc[2][mi][ni][rg]);
      }
  __syncthreads();
  {
    int d = tid >> 2, c0 = (tid & 3) * 16;
    int b_ = m0 >> 10, keybase = m0 & 1023;
    unsigned short* dst = vbt + ((size_t)((blockIdx.x * 4 + b_) * 64 + d)) * 1024 + keybase + c0;
    #pragma unroll
    for (int i = 0; i < 16; i += 4)
      *(ushort4*)(dst + i) = *(const ushort4*)&sm[d * 72 + c0 + i];
  }
}

// =============== MFMA bf16 GEMM, 64x64 tile, BK=64 (modes 1..3) ===============
// MODE>=2 degeneracy: per-block decision (R16-proven), zero barriers, no flags kernel.
template<int MODE>
__global__ void __launch_bounds__(256) gemm64(
    const unsigned short* __restrict__ Abf,
    const unsigned short* __restrict__ BT,
    unsigned short* __restrict__ o0,
    float* __restrict__ outF,
    const float* __restrict__ residF,
    const float* __restrict__ biasF,
    const float* __restrict__ hn,
    const float* __restrict__ cn)
{
  __shared__ unsigned short Asm[2][2048];
  __shared__ unsigned short Bsm[2][2048];
  int tid = threadIdx.x;
  int m0 = blockIdx.y * 64, n0 = blockIdx.x * 64;

  if (MODE >= 2) {
    int lane0 = tid & 63;
    float cm = 0.f;
    #pragma unroll
    for (int j = 0; j < 12; j++) cm = fmaxf(cm, cn[lane0 + 64 * j]);
    #pragma unroll
    for (int m = 1; m < 64; m <<= 1) cm = fmaxf(cm, __shfl_xor(cm, m));
    float hm = hn[m0 + lane0];
    #pragma unroll
    for (int m = 1; m < 64; m <<= 1) hm = fminf(hm, __shfl_xor(hm, m));
    float a = sqrtf(hm), bq = sqrtf(cm);
    bool allz = (a > bq) && ((a - bq) * (a - bq) > 300.0f);
    if (allz) return;   // MODE 2: Km rows zero & unread; MODE 3: out written by ln2
  }

  int lane = tid & 63, wave = tid >> 6;
  int quad = lane >> 4, l15 = lane & 15;
  int wr = (wave >> 1) << 5, wc = (wave & 1) << 5;

  f32x4 acc[2][2];
  #pragma unroll
  for (int i = 0; i < 2; i++)
    #pragma unroll
    for (int j = 0; j < 2; j++) acc[i][j] = (f32x4){0.f, 0.f, 0.f, 0.f};

  const unsigned short* gA = Abf + (size_t)(m0 + (tid >> 2)) * Dm + ((tid & 3) << 3);
  const unsigned short* gB = BT  + (size_t)(n0 + (tid >> 2)) * Dm + ((tid & 3) << 3);

  union Frag { bf16x8 v; ushort4 h[2]; };

  for (int k0 = 0; k0 < Dm; k0 += 64) {
    gl_lds16(gA + k0,      &Asm[0][tid * 8]);
    gl_lds16(gA + k0 + 32, &Asm[1][tid * 8]);
    gl_lds16(gB + k0,      &Bsm[0][tid * 8]);
    gl_lds16(gB + k0 + 32, &Bsm[1][tid * 8]);
    __syncthreads();
    #pragma unroll
    for (int kc = 0; kc < 2; kc++) {
      Frag af[2], bfb[2];
      #pragma unroll
      for (int i = 0; i < 2; i++) {
        af[i].v  = *(const bf16x8*)&Asm[kc][(wr + i * 16 + l15) * 32 + quad * 8];
        bfb[i].v = *(const bf16x8*)&Bsm[kc][(wc + i * 16 + l15) * 32 + quad * 8];
      }
      #pragma unroll
      for (int mi = 0; mi < 2; mi++)
        #pragma unroll
        for (int ni = 0; ni < 2; ni++)
          acc[mi][ni] = __builtin_amdgcn_mfma_f32_16x16x32_bf16(
              af[mi].v, bfb[ni].v, acc[mi][ni], 0, 0, 0);
    }
    __syncthreads();
  }

  #pragma unroll
  for (int mi = 0; mi < 2; mi++)
    #pragma unroll
    for (int ni = 0; ni < 2; ni++)
      #pragma unroll
      for (int rg = 0; rg < 4; rg++) {
        int gr = m0 + wr + mi * 16 + quad * 4 + rg;
        int gc = n0 + wc + ni * 16 + l15;
        size_t idx = (size_t)gr * Dm + gc;
        float v = acc[mi][ni][rg];
        if (MODE == 2) {
          float sq = fmaxf(hn[gr] + cn[gc] - 2.0f * v, 0.f);
          o0[idx] = f2bf(__expf(-0.5f * sq));
        } else {
          outF[idx] = residF[idx] + v + biasF[gc];
        }
      }
}

// =============== flash attention v7.2 (R15-proven): CU-load-balanced qt, swapped-QK^T ===============
__global__ void __launch_bounds__(256) attn_flash(
    const unsigned short* __restrict__ q,
    const unsigned short* __restrict__ k,
    const unsigned short* __restrict__ vbt,
    unsigned short* __restrict__ ctx)
{
  int bx = blockIdx.x;
  int h  = blockIdx.y;
  int b  = blockIdx.z;
  int v  = (bx & 1) ? (15 - (bx >> 1)) : (bx >> 1);   // zigzag base
  int s  = (h + 12 * b) >> 4;                          // co-residency slot 0/1/2
  int qt;
  if (s == 0)      qt = v;
  else if (s == 1) qt = (v & 1) ? (15 - (v >> 1)) : (7 - (v >> 1));
  else             qt = (v & 1) ? (7  - (v >> 1)) : (15 - (v >> 1));

  int tid = threadIdx.x;
  int lane = tid & 63, wave = tid >> 6;
  int quad = lane >> 4, l15 = lane & 15;

  __shared__ unsigned short Ks[2][2][2048];   // [buf][kc]
  __shared__ unsigned short Vt[2][2][2048];
  __shared__ unsigned short QP[4608];         // Q staging, then P[64][72] scratch

  size_t baseQK = (size_t)(b * Ls) * Dm + h * HD;
  const unsigned short* gVt = vbt + (size_t)((h * 4 + b) * 64 + (tid >> 2)) * 1024 + ((tid & 3) << 3);

  {
    const unsigned short* gQ = q + baseQK + (size_t)(qt * 64 + (tid >> 2)) * Dm + ((tid & 3) << 3);
    gl_lds16(gQ,      &QP[tid * 8]);
    gl_lds16(gQ + 32, &QP[2048 + tid * 8]);
  }
  __syncthreads();

  union Frag { bf16x8 v; ushort4 h[2]; };
  Frag afq[2];
  #pragma unroll
  for (int kc = 0; kc < 2; kc++)
    afq[kc].v = *(const bf16x8*)&QP[kc * 2048 + (wave * 16 + l15) * 32 + quad * 8];
  asm volatile("s_waitcnt lgkmcnt(0)" ::: "memory");   // QP reused as P scratch below

  f32x4 O[4];
  #pragma unroll
  for (int nj = 0; nj < 4; nj++) O[nj] = (f32x4){0.f, 0.f, 0.f, 0.f};
  float lsum1 = 0.f;    // all 16 p's per tile belong to q = wave*16+l15

  const unsigned short* gK = k + baseQK + (size_t)(tid >> 2) * Dm + ((tid & 3) << 3);

  gl_lds16(gK,      &Ks[0][0][tid * 8]);
  gl_lds16(gK + 32, &Ks[0][1][tid * 8]);
  gl_lds16(gVt,      &Vt[0][0][tid * 8]);
  gl_lds16(gVt + 32, &Vt[0][1][tid * 8]);

  for (int kt = 0; kt <= qt; kt++) {
    int cur = kt & 1;
    asm volatile("s_waitcnt lgkmcnt(0)" ::: "memory");
    __builtin_amdgcn_s_barrier();
    if (kt < qt) {
      int nxt = cur ^ 1;
      gl_lds16(gK + (size_t)((kt + 1) * 64) * Dm,      &Ks[nxt][0][tid * 8]);
      gl_lds16(gK + (size_t)((kt + 1) * 64) * Dm + 32, &Ks[nxt][1][tid * 8]);
      gl_lds16(gVt + (kt + 1) * 64,      &Vt[nxt][0][tid * 8]);
      gl_lds16(gVt + (kt + 1) * 64 + 32, &Vt[nxt][1][tid * 8]);
      asm volatile("s_waitcnt vmcnt(4)" ::: "memory");
    } else {
      asm volatile("s_waitcnt vmcnt(0)" ::: "memory");
    }
    __builtin_amdgcn_s_barrier();
    __builtin_amdgcn_sched_barrier(0);

    // S^T: sacc[ni] holds S^T[key = ni*16+quad*4+rg][q = wave*16+l15] (already /8)
    f32x4 sacc[4];
    #pragma unroll
    for (int ni = 0; ni < 4; ni++) {
      sacc[ni] = (f32x4){0.f, 0.f, 0.f, 0.f};
      #pragma unroll
      for (int kc = 0; kc < 2; kc++) {
        Frag bk;
        bk.v = *(const bf16x8*)&Ks[cur][kc][(ni * 16 + l15) * 32 + quad * 8];
        sacc[ni] = __builtin_amdgcn_mfma_f32_16x16x32_bf16(bk.v, afq[kc].v, sacc[ni], 0, 0, 0);
      }
    }

    if (kt == qt) {   // causal: mask keys > q
      #pragma unroll
      for (int ni = 0; ni < 4; ni++)
        #pragma unroll
        for (int rg = 0; rg < 4; rg++)
          if (ni * 16 + quad * 4 + rg > wave * 16 + l15) sacc[ni][rg] = -1e30f;
    }

    // softmax + pack: P[q][key] with 4 contiguous keys per ni -> 1 ds_write_b64 each
    unsigned short (*Ps)[72] = (unsigned short(*)[72])QP;
    #pragma unroll
    for (int ni = 0; ni < 4; ni++) {
      float p0 = __expf(sacc[ni][0]);
      float p1 = __expf(sacc[ni][1]);
      float p2 = __expf(sacc[ni][2]);
      float p3 = __expf(sacc[ni][3]);
      lsum1 += (p0 + p1) + (p2 + p3);
      unsigned int dw0, dw1;
      asm("v_cvt_pk_bf16_f32 %0, %1, %2" : "=v"(dw0) : "v"(p0), "v"(p1));
      asm("v_cvt_pk_bf16_f32 %0, %1, %2" : "=v"(dw1) : "v"(p2), "v"(p3));
      uint2 dq; dq.x = dw0; dq.y = dw1;
      *(uint2*)&Ps[wave * 16 + l15][ni * 16 + quad * 4] = dq;
    }
    asm volatile("s_waitcnt lgkmcnt(0)" ::: "memory");   // P writes visible to own-wave reads
    __builtin_amdgcn_sched_barrier(0);                   // rule #18: pin MFMA after the wait

    Frag ap[2];
    #pragma unroll
    for (int kc = 0; kc < 2; kc++)
      ap[kc].v = *(const bf16x8*)&Ps[wave * 16 + l15][kc * 32 + quad * 8];

    #pragma unroll
    for (int nj = 0; nj < 4; nj++)
      #pragma unroll
      for (int kc = 0; kc < 2; kc++) {
        Frag bv;
        bv.v = *(const bf16x8*)&Vt[cur][kc][(nj * 16 + l15) * 32 + quad * 8];
        O[nj] = __builtin_amdgcn_mfma_f32_16x16x32_bf16(ap[kc].v, bv.v, O[nj], 0, 0, 0);
      }
  }

  // lsum: sum across the 4 quad-lanes sharing q=l15, then fetch per-output-row value
  float lq = lsum1;
  lq += __shfl_xor(lq, 16);
  lq += __shfl_xor(lq, 32);
  float linv[4];
  #pragma unroll
  for (int rg = 0; rg < 4; rg++)
    linv[rg] = 1.0f / __shfl(lq, quad * 4 + rg, 64);   // lane (quad_p=0, l15=quad*4+rg)

  #pragma unroll
  for (int nj = 0; nj < 4; nj++)
    #pragma unroll
    for (int rg = 0; rg < 4; rg++) {
      int row = qt * 64 + wave * 16 + quad * 4 + rg;
      int col = nj * 16 + l15;
      ctx[baseQK + (size_t)row * Dm + col] = f2bf(O[nj][rg] * linv[rg]);
    }
}

extern "C" void kernel_launch(void* const* d_in, const int* in_sizes, int n_in,
                              void* d_out, int out_size, void* d_ws, size_t ws_size,
                              hipStream_t stream)
{
  const float* x      = (const float*)d_in[0];
  const float* Wq     = (const float*)d_in[1];
  const float* Wk     = (const float*)d_in[2];
  const float* Wv     = (const float*)d_in[3];
  const float* Wo     = (const float*)d_in[4];
  const float* bo     = (const float*)d_in[5];
  const float* scale1 = (const float*)d_in[6];
  const float* shift1 = (const float*)d_in[7];
  const float* scale2 = (const float*)d_in[8];
  const float* shift2 = (const float*)d_in[9];
  const float* centers= (const float*)d_in[10];
  const float* lsp    = (const float*)d_in[11];
  const float* Wf     = (const float*)d_in[12];
  const float* bfv    = (const float*)d_in[13];
  float* out = (float*)d_out;

  unsigned short* wsu = (unsigned short*)d_ws;
  unsigned short* wqT = wsu;
  unsigned short* wkT = wsu + WSZ;
  unsigned short* wvT = wsu + 2 * WSZ;
  unsigned short* woT = wsu + 3 * WSZ;
  unsigned short* wfT = wsu + 4 * WSZ;
  unsigned short* cb  = wsu + 5 * WSZ;
  unsigned short* bufA = wsu + 6 * WSZ;
  unsigned short* bufB = bufA + S;
  unsigned short* hb  = bufA;
  unsigned short* qb  = bufB;
  unsigned short* kb  = bufB + S;
  unsigned short* vbt = bufB + 2 * S;
  unsigned short* ctx = bufA;
  float* x1f          = (float*)bufB;
  unsigned short* hf  = bufB + 2 * S;
  unsigned short* Km  = bufA;
  float* hn = (float*)(bufB + 3 * S);
  float* cn = hn + ROWS;

  dim3 gg(Dm / 64, ROWS / 64);         // (12, 64)

  // R17 MEASUREMENT: prep launched twice (idempotent, stream-ordered).
  // dur_us delta vs R16 (166.3) == prep's cost. Decision rule: delta <= 13us -> all
  // components at structural ceilings; delta >= 18us -> prep has a fixable defect.
  prep_kernel<<<1936, 256, 0, stream>>>(Wq, Wk, Wv, Wo, Wf, wsu,
                                        centers, lsp, cb, cn,
                                        x, scale1, shift1, hb);
  prep_kernel<<<1936, 256, 0, stream>>>(Wq, Wk, Wv, Wo, Wf, wsu,
                                        centers, lsp, cb, cn,
                                        x, scale1, shift1, hb);
  gemm_qkv<<<dim3(12, 64), 256, 0, stream>>>(hb, wqT, wkT, wvT, qb, kb, vbt);
  attn_flash<<<dim3(Ls / 64, Hh, Bb), 256, 0, stream>>>(qb, kb, vbt, ctx);
  gemm64<1><<<gg, 256, 0, stream>>>(ctx, woT, nullptr, x1f, x, bo, nullptr, nullptr);
  ln2_kernel<<<ROWS / 4, 256, 0, stream>>>(x1f, scale2, shift2, lsp, cn, bfv, hf, hn, out);
  gemm64<2><<<gg, 256, 0, stream>>>(hf, cb, Km, nullptr, nullptr, nullptr, hn, cn);
  gemm64<3><<<gg, 256, 0, stream>>>(Km, wfT, nullptr, out, x1f, bfv, hn, cn);
}

// Round 18
// 164.766 us; speedup vs baseline: 1.0484x; 1.0484x over previous
//
#include <hip/hip_runtime.h>

#define EPS_LN 1e-5f

constexpr int Dm   = 768;
constexpr int Bb   = 4;
constexpr int Ls   = 1024;
constexpr int Hh   = 12;
constexpr int HD   = 64;
constexpr int ROWS = Bb * Ls;            // 4096
constexpr size_t S = (size_t)ROWS * Dm;  // 3,145,728
constexpr size_t WSZ = (size_t)Dm * Dm;  // 589,824

typedef __attribute__((ext_vector_type(8))) short bf16x8;
typedef __attribute__((ext_vector_type(4))) float f32x4;
typedef const __attribute__((address_space(1))) unsigned int* gas_p;
typedef __attribute__((address_space(3))) unsigned int* las_p;

__device__ __forceinline__ unsigned short f2bf(float f) {
  unsigned int u = __float_as_uint(f);
  u += 0x7fffu + ((u >> 16) & 1u);   // RNE
  return (unsigned short)(u >> 16);
}
__device__ __forceinline__ void gl_lds16(const unsigned short* g, unsigned short* l) {
  __builtin_amdgcn_global_load_lds((gas_p)g, (las_p)l, 16, 0, 0);
}

// =============== fused prep: 5 weight transposes + centers(wave-per-row) + LN1(wave-per-row) ===============
// R17 measured: 6.4 us total (~85% of achievable HBM BW for its 35 MB) — at ceiling.
__global__ void __launch_bounds__(256) prep_kernel(
    const float* __restrict__ W0, const float* __restrict__ W1,
    const float* __restrict__ W2, const float* __restrict__ W3,
    const float* __restrict__ W4, unsigned short* __restrict__ wtBase,
    const float* __restrict__ centers, const float* __restrict__ ls,
    unsigned short* __restrict__ cb, float* __restrict__ cn,
    const float* __restrict__ x, const float* __restrict__ scale,
    const float* __restrict__ shift, unsigned short* __restrict__ hb)
{
  __shared__ float smem[64 * 65];
  int bx = blockIdx.x, t = threadIdx.x;
  if (bx < 720) {
    int w = bx / 144, rem = bx - w * 144;
    int ky = rem / 12, nx = rem - ky * 12;
    const float* W = w == 0 ? W0 : w == 1 ? W1 : w == 2 ? W2 : w == 3 ? W3 : W4;
    unsigned short* WT = wtBase + (size_t)w * WSZ;
    int k0 = ky * 64, n0 = nx * 64;
    int c = t & 63, r4 = t >> 6;
    #pragma unroll
    for (int p = 0; p < 16; p++) {
      int r = p * 4 + r4;
      smem[r * 65 + c] = W[(size_t)(k0 + r) * Dm + n0 + c];
    }
    __syncthreads();
    #pragma unroll
    for (int p = 0; p < 16; p++) {
      int r = p * 4 + r4;
      WT[(size_t)(n0 + r) * Dm + k0 + c] = f2bf(smem[c * 65 + r]);
    }
  } else if (bx < 912) {
    // centers: wave-per-row, zero barriers
    int lane = t & 63;
    int j = (bx - 720) * 4 + (t >> 6);
    size_t base = (size_t)j * Dm;
    float s = 0.f;
    #pragma unroll
    for (int jj = 0; jj < 3; jj++) {
      int k4 = 4 * (lane + 64 * jj);
      float4 cv = *(const float4*)&centers[base + k4];
      float4 lv = *(const float4*)&ls[k4];
      float4 c;
      c.x = cv.x / lv.x; c.y = cv.y / lv.y; c.z = cv.z / lv.z; c.w = cv.w / lv.w;
      ushort4 o4;
      o4.x = f2bf(c.x); o4.y = f2bf(c.y); o4.z = f2bf(c.z); o4.w = f2bf(c.w);
      *(ushort4*)&cb[base + k4] = o4;
      s += c.x*c.x + c.y*c.y + c.z*c.z + c.w*c.w;
    }
    #pragma unroll
    for (int m = 1; m < 64; m <<= 1) s += __shfl_xor(s, m);
    if (lane == 0) cn[j] = s;
  } else {
    // LN1: wave-per-row, zero barriers
    int lane = t & 63;
    int row = (bx - 912) * 4 + (t >> 6);
    size_t base = (size_t)row * Dm;
    float4 v[3];
    #pragma unroll
    for (int j = 0; j < 3; j++)
      v[j] = *(const float4*)&x[base + 4 * (lane + 64 * j)];
    float sum = 0.f;
    #pragma unroll
    for (int j = 0; j < 3; j++) sum += v[j].x + v[j].y + v[j].z + v[j].w;
    #pragma unroll
    for (int m = 1; m < 64; m <<= 1) sum += __shfl_xor(sum, m);
    float mean = sum * (1.0f / Dm);
    float4 d[3];
    float vs = 0.f;
    #pragma unroll
    for (int j = 0; j < 3; j++) {
      d[j].x = v[j].x - mean; d[j].y = v[j].y - mean;
      d[j].z = v[j].z - mean; d[j].w = v[j].w - mean;
      vs += d[j].x*d[j].x + d[j].y*d[j].y + d[j].z*d[j].z + d[j].w*d[j].w;
    }
    #pragma unroll
    for (int m = 1; m < 64; m <<= 1) vs += __shfl_xor(vs, m);
    float rstd = rsqrtf(vs * (1.0f / Dm) + EPS_LN);
    #pragma unroll
    for (int j = 0; j < 3; j++) {
      int c4 = 4 * (lane + 64 * j);
      float4 sc = *(const float4*)&scale[c4];
      float4 sh = *(const float4*)&shift[c4];
      ushort4 o4;
      o4.x = f2bf(sc.x * d[j].x * rstd + sh.x);
      o4.y = f2bf(sc.y * d[j].y * rstd + sh.y);
      o4.z = f2bf(sc.z * d[j].z * rstd + sh.z);
      o4.w = f2bf(sc.w * d[j].w * rstd + sh.w);
      *(ushort4*)&hb[base + c4] = o4;
    }
  }
}

// ---- LN2 + /ls (wave-per-row) + fused degenerate-RBF output (R12-proven) ----
__global__ void __launch_bounds__(256) ln2_kernel(
    const float* __restrict__ xin, const float* __restrict__ scale,
    const float* __restrict__ shift, const float* __restrict__ ls,
    const float* __restrict__ cn, const float* __restrict__ bias,
    unsigned short* __restrict__ o, float* __restrict__ hn,
    float* __restrict__ outF)
{
  int lane = threadIdx.x & 63;
  int row = blockIdx.x * 4 + (threadIdx.x >> 6);
  size_t base = (size_t)row * Dm;
  float4 v[3];
  #pragma unroll
  for (int j = 0; j < 3; j++)
    v[j] = *(const float4*)&xin[base + 4 * (lane + 64 * j)];
  float sum = 0.f;
  #pragma unroll
  for (int j = 0; j < 3; j++) sum += v[j].x + v[j].y + v[j].z + v[j].w;
  #pragma unroll
  for (int m = 1; m < 64; m <<= 1) sum += __shfl_xor(sum, m);
  float mean = sum * (1.0f / Dm);
  float4 d[3];
  float vs = 0.f;
  #pragma unroll
  for (int j = 0; j < 3; j++) {
    d[j].x = v[j].x - mean; d[j].y = v[j].y - mean;
    d[j].z = v[j].z - mean; d[j].w = v[j].w - mean;
    vs += d[j].x*d[j].x + d[j].y*d[j].y + d[j].z*d[j].z + d[j].w*d[j].w;
  }
  #pragma unroll
  for (int m = 1; m < 64; m <<= 1) vs += __shfl_xor(vs, m);
  float rstd = rsqrtf(vs * (1.0f / Dm) + EPS_LN);
  float hsum = 0.f;
  #pragma unroll
  for (int j = 0; j < 3; j++) {
    int c4 = 4 * (lane + 64 * j);
    float4 sc = *(const float4*)&scale[c4];
    float4 sh = *(const float4*)&shift[c4];
    float4 lv = *(const float4*)&ls[c4];
    float4 hv;
    hv.x = (sc.x * d[j].x * rstd + sh.x) / lv.x;
    hv.y = (sc.y * d[j].y * rstd + sh.y) / lv.y;
    hv.z = (sc.z * d[j].z * rstd + sh.z) / lv.z;
    hv.w = (sc.w * d[j].w * rstd + sh.w) / lv.w;
    ushort4 o4;
    o4.x = f2bf(hv.x); o4.y = f2bf(hv.y); o4.z = f2bf(hv.z); o4.w = f2bf(hv.w);
    *(ushort4*)&o[base + c4] = o4;
    hsum += hv.x*hv.x + hv.y*hv.y + hv.z*hv.z + hv.w*hv.w;
  }
  #pragma unroll
  for (int m = 1; m < 64; m <<= 1) hsum += __shfl_xor(hsum, m);
  if (lane == 0) hn[row] = hsum;

  float cm = 0.f;
  #pragma unroll
  for (int j = 0; j < 12; j++) cm = fmaxf(cm, cn[lane + 64 * j]);
  #pragma unroll
  for (int m = 1; m < 64; m <<= 1) cm = fmaxf(cm, __shfl_xor(cm, m));
  float a = sqrtf(hsum), bq = sqrtf(cm);
  if ((a > bq) && ((a - bq) * (a - bq) > 300.0f)) {
    #pragma unroll
    for (int j = 0; j < 3; j++) {
      int c4 = 4 * (lane + 64 * j);
      float4 xv = v[j];
      float4 bv = *(const float4*)&bias[c4];
      float4 ov;
      ov.x = xv.x + bv.x; ov.y = xv.y + bv.y; ov.z = xv.z + bv.z; ov.w = xv.w + bv.w;
      *(float4*)&outF[base + c4] = ov;
    }
  }
}

// =============== QKV 3-in-1 GEMM (R0-proven) + Q pre-scaled by 0.125 (exact) ===============
__global__ void __launch_bounds__(256) gemm_qkv(
    const unsigned short* __restrict__ Abf,
    const unsigned short* __restrict__ wqT,
    const unsigned short* __restrict__ wkT,
    const unsigned short* __restrict__ wvT,
    unsigned short* __restrict__ qb,
    unsigned short* __restrict__ kb,
    unsigned short* __restrict__ vbt)
{
  int m0 = blockIdx.y * 64, n0 = blockIdx.x * 64;
  __shared__ unsigned short sm[4096 + 3 * 4096];
  int tid = threadIdx.x;
  int lane = tid & 63, wave = tid >> 6;
  int quad = lane >> 4, l15 = lane & 15;
  int wr = (wave >> 1) << 5, wc = (wave & 1) << 5;

  f32x4 acc[3][2][2];
  #pragma unroll
  for (int w = 0; w < 3; w++)
    #pragma unroll
    for (int i = 0; i < 2; i++)
      #pragma unroll
      for (int j = 0; j < 2; j++) acc[w][i][j] = (f32x4){0.f, 0.f, 0.f, 0.f};

  const unsigned short* gA = Abf + (size_t)(m0 + (tid >> 2)) * Dm + ((tid & 3) << 3);
  size_t bOff = (size_t)(n0 + (tid >> 2)) * Dm + ((tid & 3) << 3);
  const unsigned short* gB[3] = { wqT + bOff, wkT + bOff, wvT + bOff };

  union Frag { bf16x8 v; ushort4 h[2]; };

  for (int k0 = 0; k0 < Dm; k0 += 64) {
    gl_lds16(gA + k0,      &sm[tid * 8]);
    gl_lds16(gA + k0 + 32, &sm[2048 + tid * 8]);
    #pragma unroll
    for (int w = 0; w < 3; w++) {
      gl_lds16(gB[w] + k0,      &sm[4096 + w * 4096 + tid * 8]);
      gl_lds16(gB[w] + k0 + 32, &sm[4096 + w * 4096 + 2048 + tid * 8]);
    }
    __syncthreads();
    Frag af[2][2];
    #pragma unroll
    for (int kc = 0; kc < 2; kc++)
      #pragma unroll
      for (int mi = 0; mi < 2; mi++)
        af[kc][mi].v = *(const bf16x8*)&sm[kc * 2048 + (wr + mi * 16 + l15) * 32 + quad * 8];
    #pragma unroll
    for (int w = 0; w < 3; w++)
      #pragma unroll
      for (int kc = 0; kc < 2; kc++)
        #pragma unroll
        for (int ni = 0; ni < 2; ni++) {
          Frag bf;
          bf.v = *(const bf16x8*)&sm[4096 + w * 4096 + kc * 2048 + (wc + ni * 16 + l15) * 32 + quad * 8];
          #pragma unroll
          for (int mi = 0; mi < 2; mi++)
            acc[w][mi][ni] = __builtin_amdgcn_mfma_f32_16x16x32_bf16(
                af[kc][mi].v, bf.v, acc[w][mi][ni], 0, 0, 0);
        }
    __syncthreads();
  }

  #pragma unroll
  for (int w = 0; w < 2; w++) {
    unsigned short* ob = w ? kb : qb;
    float scl = w ? 1.0f : 0.125f;     // Q pre-scale (exact)
    #pragma unroll
    for (int mi = 0; mi < 2; mi++)
      #pragma unroll
      for (int ni = 0; ni < 2; ni++)
        #pragma unroll
        for (int rg = 0; rg < 4; rg++) {
          int gr = m0 + wr + mi * 16 + quad * 4 + rg;
          int gc = n0 + wc + ni * 16 + l15;
          ob[(size_t)gr * Dm + gc] = f2bf(acc[w][mi][ni][rg] * scl);
        }
  }
  #pragma unroll
  for (int mi = 0; mi < 2; mi++)
    #pragma unroll
    for (int ni = 0; ni < 2; ni++)
      #pragma unroll
      for (int rg = 0; rg < 4; rg++) {
        int rl = wr + mi * 16 + quad * 4 + rg;
        int cl = wc + ni * 16 + l15;
        sm[cl * 72 + rl] = f2bf(acc[2][mi][ni][rg]);
      }
  __syncthreads();
  {
    int d = tid >> 2, c0 = (tid & 3) * 16;
    int b_ = m0 >> 10, keybase = m0 & 1023;
    unsigned short* dst = vbt + ((size_t)((blockIdx.x * 4 + b_) * 64 + d)) * 1024 + keybase + c0;
    #pragma unroll
    for (int i = 0; i < 16; i += 4)
      *(ushort4*)(dst + i) = *(const ushort4*)&sm[d * 72 + c0 + i];
  }
}

// =============== MFMA bf16 GEMM, 64x64 tile, BK=64 (modes 1..3) ===============
// MODE>=2 degeneracy: per-block decision (R16-proven), zero barriers, no flags kernel.
template<int MODE>
__global__ void __launch_bounds__(256) gemm64(
    const unsigned short* __restrict__ Abf,
    const unsigned short* __restrict__ BT,
    unsigned short* __restrict__ o0,
    float* __restrict__ outF,
    const float* __restrict__ residF,
    const float* __restrict__ biasF,
    const float* __restrict__ hn,
    const float* __restrict__ cn)
{
  __shared__ unsigned short Asm[2][2048];
  __shared__ unsigned short Bsm[2][2048];
  int tid = threadIdx.x;
  int m0 = blockIdx.y * 64, n0 = blockIdx.x * 64;

  if (MODE >= 2) {
    int lane0 = tid & 63;
    float cm = 0.f;
    #pragma unroll
    for (int j = 0; j < 12; j++) cm = fmaxf(cm, cn[lane0 + 64 * j]);
    #pragma unroll
    for (int m = 1; m < 64; m <<= 1) cm = fmaxf(cm, __shfl_xor(cm, m));
    float hm = hn[m0 + lane0];
    #pragma unroll
    for (int m = 1; m < 64; m <<= 1) hm = fminf(hm, __shfl_xor(hm, m));
    float a = sqrtf(hm), bq = sqrtf(cm);
    bool allz = (a > bq) && ((a - bq) * (a - bq) > 300.0f);
    if (allz) return;   // MODE 2: Km rows zero & unread; MODE 3: out written by ln2
  }

  int lane = tid & 63, wave = tid >> 6;
  int quad = lane >> 4, l15 = lane & 15;
  int wr = (wave >> 1) << 5, wc = (wave & 1) << 5;

  f32x4 acc[2][2];
  #pragma unroll
  for (int i = 0; i < 2; i++)
    #pragma unroll
    for (int j = 0; j < 2; j++) acc[i][j] = (f32x4){0.f, 0.f, 0.f, 0.f};

  const unsigned short* gA = Abf + (size_t)(m0 + (tid >> 2)) * Dm + ((tid & 3) << 3);
  const unsigned short* gB = BT  + (size_t)(n0 + (tid >> 2)) * Dm + ((tid & 3) << 3);

  union Frag { bf16x8 v; ushort4 h[2]; };

  for (int k0 = 0; k0 < Dm; k0 += 64) {
    gl_lds16(gA + k0,      &Asm[0][tid * 8]);
    gl_lds16(gA + k0 + 32, &Asm[1][tid * 8]);
    gl_lds16(gB + k0,      &Bsm[0][tid * 8]);
    gl_lds16(gB + k0 + 32, &Bsm[1][tid * 8]);
    __syncthreads();
    #pragma unroll
    for (int kc = 0; kc < 2; kc++) {
      Frag af[2], bfb[2];
      #pragma unroll
      for (int i = 0; i < 2; i++) {
        af[i].v  = *(const bf16x8*)&Asm[kc][(wr + i * 16 + l15) * 32 + quad * 8];
        bfb[i].v = *(const bf16x8*)&Bsm[kc][(wc + i * 16 + l15) * 32 + quad * 8];
      }
      #pragma unroll
      for (int mi = 0; mi < 2; mi++)
        #pragma unroll
        for (int ni = 0; ni < 2; ni++)
          acc[mi][ni] = __builtin_amdgcn_mfma_f32_16x16x32_bf16(
              af[mi].v, bfb[ni].v, acc[mi][ni], 0, 0, 0);
    }
    __syncthreads();
  }

  #pragma unroll
  for (int mi = 0; mi < 2; mi++)
    #pragma unroll
    for (int ni = 0; ni < 2; ni++)
      #pragma unroll
      for (int rg = 0; rg < 4; rg++) {
        int gr = m0 + wr + mi * 16 + quad * 4 + rg;
        int gc = n0 + wc + ni * 16 + l15;
        size_t idx = (size_t)gr * Dm + gc;
        float v = acc[mi][ni][rg];
        if (MODE == 2) {
          float sq = fmaxf(hn[gr] + cn[gc] - 2.0f * v, 0.f);
          o0[idx] = f2bf(__expf(-0.5f * sq));
        } else {
          outF[idx] = residF[idx] + v + biasF[gc];
        }
      }
}

// =============== flash attention v7.2 (R15-proven): CU-load-balanced qt, swapped-QK^T ===============
__global__ void __launch_bounds__(256) attn_flash(
    const unsigned short* __restrict__ q,
    const unsigned short* __restrict__ k,
    const unsigned short* __restrict__ vbt,
    unsigned short* __restrict__ ctx)
{
  int bx = blockIdx.x;
  int h  = blockIdx.y;
  int b  = blockIdx.z;
  int v  = (bx & 1) ? (15 - (bx >> 1)) : (bx >> 1);   // zigzag base
  int s  = (h + 12 * b) >> 4;                          // co-residency slot 0/1/2
  int qt;
  if (s == 0)      qt = v;
  else if (s == 1) qt = (v & 1) ? (15 - (v >> 1)) : (7 - (v >> 1));
  else             qt = (v & 1) ? (7  - (v >> 1)) : (15 - (v >> 1));

  int tid = threadIdx.x;
  int lane = tid & 63, wave = tid >> 6;
  int quad = lane >> 4, l15 = lane & 15;

  __shared__ unsigned short Ks[2][2][2048];   // [buf][kc]
  __shared__ unsigned short Vt[2][2][2048];
  __shared__ unsigned short QP[4608];         // Q staging, then P[64][72] scratch

  size_t baseQK = (size_t)(b * Ls) * Dm + h * HD;
  const unsigned short* gVt = vbt + (size_t)((h * 4 + b) * 64 + (tid >> 2)) * 1024 + ((tid & 3) << 3);

  {
    const unsigned short* gQ = q + baseQK + (size_t)(qt * 64 + (tid >> 2)) * Dm + ((tid & 3) << 3);
    gl_lds16(gQ,      &QP[tid * 8]);
    gl_lds16(gQ + 32, &QP[2048 + tid * 8]);
  }
  __syncthreads();

  union Frag { bf16x8 v; ushort4 h[2]; };
  Frag afq[2];
  #pragma unroll
  for (int kc = 0; kc < 2; kc++)
    afq[kc].v = *(const bf16x8*)&QP[kc * 2048 + (wave * 16 + l15) * 32 + quad * 8];
  asm volatile("s_waitcnt lgkmcnt(0)" ::: "memory");   // QP reused as P scratch below

  f32x4 O[4];
  #pragma unroll
  for (int nj = 0; nj < 4; nj++) O[nj] = (f32x4){0.f, 0.f, 0.f, 0.f};
  float lsum1 = 0.f;    // all 16 p's per tile belong to q = wave*16+l15

  const unsigned short* gK = k + baseQK + (size_t)(tid >> 2) * Dm + ((tid & 3) << 3);

  gl_lds16(gK,      &Ks[0][0][tid * 8]);
  gl_lds16(gK + 32, &Ks[0][1][tid * 8]);
  gl_lds16(gVt,      &Vt[0][0][tid * 8]);
  gl_lds16(gVt + 32, &Vt[0][1][tid * 8]);

  for (int kt = 0; kt <= qt; kt++) {
    int cur = kt & 1;
    asm volatile("s_waitcnt lgkmcnt(0)" ::: "memory");
    __builtin_amdgcn_s_barrier();
    if (kt < qt) {
      int nxt = cur ^ 1;
      gl_lds16(gK + (size_t)((kt + 1) * 64) * Dm,      &Ks[nxt][0][tid * 8]);
      gl_lds16(gK + (size_t)((kt + 1) * 64) * Dm + 32, &Ks[nxt][1][tid * 8]);
      gl_lds16(gVt + (kt + 1) * 64,      &Vt[nxt][0][tid * 8]);
      gl_lds16(gVt + (kt + 1) * 64 + 32, &Vt[nxt][1][tid * 8]);
      asm volatile("s_waitcnt vmcnt(4)" ::: "memory");
    } else {
      asm volatile("s_waitcnt vmcnt(0)" ::: "memory");
    }
    __builtin_amdgcn_s_barrier();
    __builtin_amdgcn_sched_barrier(0);

    // S^T: sacc[ni] holds S^T[key = ni*16+quad*4+rg][q = wave*16+l15] (already /8)
    f32x4 sacc[4];
    #pragma unroll
    for (int ni = 0; ni < 4; ni++) {
      sacc[ni] = (f32x4){0.f, 0.f, 0.f, 0.f};
      #pragma unroll
      for (int kc = 0; kc < 2; kc++) {
        Frag bk;
        bk.v = *(const bf16x8*)&Ks[cur][kc][(ni * 16 + l15) * 32 + quad * 8];
        sacc[ni] = __builtin_amdgcn_mfma_f32_16x16x32_bf16(bk.v, afq[kc].v, sacc[ni], 0, 0, 0);
      }
    }

    if (kt == qt) {   // causal: mask keys > q
      #pragma unroll
      for (int ni = 0; ni < 4; ni++)
        #pragma unroll
        for (int rg = 0; rg < 4; rg++)
          if (ni * 16 + quad * 4 + rg > wave * 16 + l15) sacc[ni][rg] = -1e30f;
    }

    // softmax + pack: P[q][key] with 4 contiguous keys per ni -> 1 ds_write_b64 each
    unsigned short (*Ps)[72] = (unsigned short(*)[72])QP;
    #pragma unroll
    for (int ni = 0; ni < 4; ni++) {
      float p0 = __expf(sacc[ni][0]);
      float p1 = __expf(sacc[ni][1]);
      float p2 = __expf(sacc[ni][2]);
      float p3 = __expf(sacc[ni][3]);
      lsum1 += (p0 + p1) + (p2 + p3);
      unsigned int dw0, dw1;
      asm("v_cvt_pk_bf16_f32 %0, %1, %2" : "=v"(dw0) : "v"(p0), "v"(p1));
      asm("v_cvt_pk_bf16_f32 %0, %1, %2" : "=v"(dw1) : "v"(p2), "v"(p3));
      uint2 dq; dq.x = dw0; dq.y = dw1;
      *(uint2*)&Ps[wave * 16 + l15][ni * 16 + quad * 4] = dq;
    }
    asm volatile("s_waitcnt lgkmcnt(0)" ::: "memory");   // P writes visible to own-wave reads
    __builtin_amdgcn_sched_barrier(0);                   // rule #18: pin MFMA after the wait

    Frag ap[2];
    #pragma unroll
    for (int kc = 0; kc < 2; kc++)
      ap[kc].v = *(const bf16x8*)&Ps[wave * 16 + l15][kc * 32 + quad * 8];

    #pragma unroll
    for (int nj = 0; nj < 4; nj++)
      #pragma unroll
      for (int kc = 0; kc < 2; kc++) {
        Frag bv;
        bv.v = *(const bf16x8*)&Vt[cur][kc][(nj * 16 + l15) * 32 + quad * 8];
        O[nj] = __builtin_amdgcn_mfma_f32_16x16x32_bf16(ap[kc].v, bv.v, O[nj], 0, 0, 0);
      }
  }

  // lsum: sum across the 4 quad-lanes sharing q=l15, then fetch per-output-row value
  float lq = lsum1;
  lq += __shfl_xor(lq, 16);
  lq += __shfl_xor(lq, 32);
  float linv[4];
  #pragma unroll
  for (int rg = 0; rg < 4; rg++)
    linv[rg] = 1.0f / __shfl(lq, quad * 4 + rg, 64);   // lane (quad_p=0, l15=quad*4+rg)

  #pragma unroll
  for (int nj = 0; nj < 4; nj++)
    #pragma unroll
    for (int rg = 0; rg < 4; rg++) {
      int row = qt * 64 + wave * 16 + quad * 4 + rg;
      int col = nj * 16 + l15;
      ctx[baseQK + (size_t)row * Dm + col] = f2bf(O[nj][rg] * linv[rg]);
    }
}

extern "C" void kernel_launch(void* const* d_in, const int* in_sizes, int n_in,
                              void* d_out, int out_size, void* d_ws, size_t ws_size,
                              hipStream_t stream)
{
  const float* x      = (const float*)d_in[0];
  const float* Wq     = (const float*)d_in[1];
  const float* Wk     = (const float*)d_in[2];
  const float* Wv     = (const float*)d_in[3];
  const float* Wo     = (const float*)d_in[4];
  const float* bo     = (const float*)d_in[5];
  const float* scale1 = (const float*)d_in[6];
  const float* shift1 = (const float*)d_in[7];
  const float* scale2 = (const float*)d_in[8];
  const float* shift2 = (const float*)d_in[9];
  const float* centers= (const float*)d_in[10];
  const float* lsp    = (const float*)d_in[11];
  const float* Wf     = (const float*)d_in[12];
  const float* bfv    = (const float*)d_in[13];
  float* out = (float*)d_out;

  unsigned short* wsu = (unsigned short*)d_ws;
  unsigned short* wqT = wsu;
  unsigned short* wkT = wsu + WSZ;
  unsigned short* wvT = wsu + 2 * WSZ;
  unsigned short* woT = wsu + 3 * WSZ;
  unsigned short* wfT = wsu + 4 * WSZ;
  unsigned short* cb  = wsu + 5 * WSZ;
  unsigned short* bufA = wsu + 6 * WSZ;
  unsigned short* bufB = bufA + S;
  unsigned short* hb  = bufA;
  unsigned short* qb  = bufB;
  unsigned short* kb  = bufB + S;
  unsigned short* vbt = bufB + 2 * S;
  unsigned short* ctx = bufA;
  float* x1f          = (float*)bufB;
  unsigned short* hf  = bufB + 2 * S;
  unsigned short* Km  = bufA;
  float* hn = (float*)(bufB + 3 * S);
  float* cn = hn + ROWS;

  dim3 gg(Dm / 64, ROWS / 64);         // (12, 64)

  // prep grid: 720 transpose + 192 centers(wave-per-row) + 1024 LN1 = 1936
  prep_kernel<<<1936, 256, 0, stream>>>(Wq, Wk, Wv, Wo, Wf, wsu,
                                        centers, lsp, cb, cn,
                                        x, scale1, shift1, hb);
  gemm_qkv<<<dim3(12, 64), 256, 0, stream>>>(hb, wqT, wkT, wvT, qb, kb, vbt);
  attn_flash<<<dim3(Ls / 64, Hh, Bb), 256, 0, stream>>>(qb, kb, vbt, ctx);
  gemm64<1><<<gg, 256, 0, stream>>>(ctx, woT, nullptr, x1f, x, bo, nullptr, nullptr);
  ln2_kernel<<<ROWS / 4, 256, 0, stream>>>(x1f, scale2, shift2, lsp, cn, bfv, hf, hn, out);
  gemm64<2><<<gg, 256, 0, stream>>>(hf, cb, Km, nullptr, nullptr, nullptr, hn, cn);
  gemm64<3><<<gg, 256, 0, stream>>>(Km, wfT, nullptr, out, x1f, bfv, hn, cn);
}